// Round 1
// baseline (366.308 us; speedup 1.0000x reference)
//
#include <hip/hip_runtime.h>
#include <hip/hip_bf16.h>
#include <cstdint>

typedef unsigned short ushort_t;
typedef __bf16 bf16x8 __attribute__((ext_vector_type(8)));
typedef float floatx4 __attribute__((ext_vector_type(4)));
typedef ushort_t ushort8 __attribute__((ext_vector_type(8)));

static __device__ __forceinline__ ushort_t f2bf(float f) {
    union { float f; uint32_t u; } x; x.f = f;
    uint32_t r = x.u + 0x7fffu + ((x.u >> 16) & 1u);   // round-to-nearest-even
    return (ushort_t)(r >> 16);
}

// ---------------------------------------------------------------------------
// Kernel 1: RWB_T[n][k] = dot(rel_features[k,:], W[n,:]) + b[n]   (bf16, [128][KP])
// Stored transposed ([N][K]) so the GEMM B-fragment load mirrors the A load.
// k >= R rows are zero (K padding contributes nothing).
// ---------------------------------------------------------------------------
__global__ void rwb_kernel(const float* __restrict__ rel, const float* __restrict__ W,
                           const float* __restrict__ b, ushort_t* __restrict__ rwbT,
                           int R, int KP) {
    const int k = blockIdx.x;        // relation index (0..KP-1)
    const int n = threadIdx.x;       // output feature (0..127)
    __shared__ float relk[128];
    if (k < R) relk[n] = rel[(size_t)k * 128 + n];
    __syncthreads();
    float acc = 0.f;
    if (k < R) {
        const float4* w4 = reinterpret_cast<const float4*>(W + (size_t)n * 128);
        const float4* r4 = reinterpret_cast<const float4*>(relk);
#pragma unroll
        for (int i = 0; i < 32; ++i) {
            float4 a = r4[i], w = w4[i];
            acc += a.x * w.x + a.y * w.y + a.z * w.z + a.w * w.w;
        }
        acc += b[n];
    }
    rwbT[(size_t)n * KP + k] = f2bf(acc);
}

// ---------------------------------------------------------------------------
// Kernel 2: S[v][r] += val  for v in {tail, head}   (fp32, [NUM_ENT][KP])
// 2 scalar atomics per fact = 4M total, random over L3-resident region.
// ---------------------------------------------------------------------------
__global__ void scatter_kernel(const int* __restrict__ heads, const int* __restrict__ tails,
                               const int* __restrict__ rels, const float* __restrict__ val,
                               float* __restrict__ S, int E, int KP) {
    const int i = blockIdx.x * blockDim.x + threadIdx.x;
    if (i >= E) return;
    const int r = rels[i];
    const float v = val[i];
    unsafeAtomicAdd(&S[(size_t)tails[i] * KP + r], v);
    unsafeAtomicAdd(&S[(size_t)heads[i] * KP + r], v);
}

// ---------------------------------------------------------------------------
// Kernel 3: out = relu(S @ RWB)  — bf16 MFMA GEMM
// M=16000 (64/block), N=128 (full), K=KP (BK=32). 4 waves: 2x2 over (64m,128n),
// each wave 32x64 -> acc[2][4] of 16x16 tiles. fp32 S converted to bf16 inline.
// ---------------------------------------------------------------------------
__global__ __launch_bounds__(256, 2) void gemm_kernel(
    const float* __restrict__ S, const ushort_t* __restrict__ rwbT,
    float* __restrict__ out, int M, int KP) {
    __shared__ ushort_t As[64 * 32];    // 4 KB  (bf16 bits)
    __shared__ ushort_t Bs[128 * 32];   // 8 KB

    const int t = threadIdx.x;
    const int lane = t & 63;
    const int wave = t >> 6;
    const int m0 = blockIdx.x * 64;
    const int wm = (wave >> 1) * 32;   // wave m offset: 0 / 32
    const int wn = (wave & 1) * 64;    // wave n offset: 0 / 64

    // staging assignments
    const int a_r = t >> 2;            // 0..63   (S row within tile)
    const int a_c = (t & 3) * 8;       // 0,8,16,24
    const int b_r = t >> 1;            // 0..127  (rwbT row = n)
    const int b_c = (t & 1) * 16;      // 0,16

    // fragment addressing
    const int fr = lane & 15;          // m (A) or n (B) within 16-tile
    const int ko = (lane >> 4) * 8;    // k offset within BK=32

    floatx4 acc[2][4] = {};

    const bool a_ok = (m0 + a_r) < M;
    const float*    aptr = S + (size_t)(m0 + a_r) * KP + a_c;
    const ushort_t* bptr = rwbT + (size_t)b_r * KP + b_c;

    for (int k0 = 0; k0 < KP; k0 += 32) {
        // stage A (fp32 -> bf16)
        ushort8 apk = {0, 0, 0, 0, 0, 0, 0, 0};
        if (a_ok) {
            float4 v0 = *reinterpret_cast<const float4*>(aptr + k0);
            float4 v1 = *reinterpret_cast<const float4*>(aptr + k0 + 4);
            apk[0] = f2bf(v0.x); apk[1] = f2bf(v0.y); apk[2] = f2bf(v0.z); apk[3] = f2bf(v0.w);
            apk[4] = f2bf(v1.x); apk[5] = f2bf(v1.y); apk[6] = f2bf(v1.z); apk[7] = f2bf(v1.w);
        }
        *reinterpret_cast<ushort8*>(&As[a_r * 32 + a_c]) = apk;
        // stage B (already bf16): 32 B per thread
        float4 w0 = *reinterpret_cast<const float4*>(bptr + k0);
        float4 w1 = *reinterpret_cast<const float4*>(bptr + k0 + 8);
        *reinterpret_cast<float4*>(&Bs[b_r * 32 + b_c]) = w0;
        *reinterpret_cast<float4*>(&Bs[b_r * 32 + b_c + 8]) = w1;
        __syncthreads();

        bf16x8 af[2], bfv[4];
#pragma unroll
        for (int mi = 0; mi < 2; ++mi)
            af[mi] = *reinterpret_cast<const bf16x8*>(&As[(wm + mi * 16 + fr) * 32 + ko]);
#pragma unroll
        for (int ni = 0; ni < 4; ++ni)
            bfv[ni] = *reinterpret_cast<const bf16x8*>(&Bs[(wn + ni * 16 + fr) * 32 + ko]);
#pragma unroll
        for (int mi = 0; mi < 2; ++mi)
#pragma unroll
            for (int ni = 0; ni < 4; ++ni)
                acc[mi][ni] = __builtin_amdgcn_mfma_f32_16x16x32_bf16(
                    af[mi], bfv[ni], acc[mi][ni], 0, 0, 0);
        __syncthreads();
    }

    // epilogue: C/D layout col=lane&15, row=(lane>>4)*4+reg  [m89-verified]
    const int rbase = (lane >> 4) * 4;
#pragma unroll
    for (int mi = 0; mi < 2; ++mi)
#pragma unroll
        for (int ni = 0; ni < 4; ++ni)
#pragma unroll
            for (int g = 0; g < 4; ++g) {
                const int m = m0 + wm + mi * 16 + rbase + g;
                const int n = wn + ni * 16 + fr;
                if (m < M) out[(size_t)m * 128 + n] = fmaxf(acc[mi][ni][g], 0.f);
            }
}

// ---------------------------------------------------------------------------
// Fallback path (only if ws too small for S): direct vector scatter into out.
// ---------------------------------------------------------------------------
__global__ void rwb_f32_kernel(const float* __restrict__ rel, const float* __restrict__ W,
                               const float* __restrict__ b, float* __restrict__ rwb, int R) {
    const int k = blockIdx.x;
    const int n = threadIdx.x;
    __shared__ float relk[128];
    relk[n] = rel[(size_t)k * 128 + n];
    __syncthreads();
    const float4* w4 = reinterpret_cast<const float4*>(W + (size_t)n * 128);
    const float4* r4 = reinterpret_cast<const float4*>(relk);
    float acc = 0.f;
#pragma unroll
    for (int i = 0; i < 32; ++i) {
        float4 a = r4[i], w = w4[i];
        acc += a.x * w.x + a.y * w.y + a.z * w.z + a.w * w.w;
    }
    rwb[(size_t)k * 128 + n] = acc + b[n];
}

__global__ void scatter_vec_kernel(const int* __restrict__ heads, const int* __restrict__ tails,
                                   const int* __restrict__ rels, const float* __restrict__ val,
                                   const float* __restrict__ rwb, float* __restrict__ out,
                                   long long nitems) {
    const long long i = (long long)blockIdx.x * blockDim.x + threadIdx.x;
    if (i >= nitems) return;
    const int e = (int)(i >> 5);
    const int c = (int)(i & 31) * 4;
    const float v = val[e];
    float4 rw = *reinterpret_cast<const float4*>(rwb + (size_t)rels[e] * 128 + c);
    float* pt = out + (size_t)tails[e] * 128 + c;
    float* ph = out + (size_t)heads[e] * 128 + c;
    unsafeAtomicAdd(pt + 0, v * rw.x); unsafeAtomicAdd(pt + 1, v * rw.y);
    unsafeAtomicAdd(pt + 2, v * rw.z); unsafeAtomicAdd(pt + 3, v * rw.w);
    unsafeAtomicAdd(ph + 0, v * rw.x); unsafeAtomicAdd(ph + 1, v * rw.y);
    unsafeAtomicAdd(ph + 2, v * rw.z); unsafeAtomicAdd(ph + 3, v * rw.w);
}

__global__ void relu_kernel(float* __restrict__ out, int n4) {
    const int i = blockIdx.x * blockDim.x + threadIdx.x;
    if (i >= n4) return;
    float4* p = reinterpret_cast<float4*>(out) + i;
    float4 v = *p;
    v.x = fmaxf(v.x, 0.f); v.y = fmaxf(v.y, 0.f);
    v.z = fmaxf(v.z, 0.f); v.w = fmaxf(v.w, 0.f);
    *p = v;
}

// ---------------------------------------------------------------------------
extern "C" void kernel_launch(void* const* d_in, const int* in_sizes, int n_in,
                              void* d_out, int out_size, void* d_ws, size_t ws_size,
                              hipStream_t stream) {
    // inputs: 0 local_entity [B*M] (shape only), 1 heads [E], 2 tails [E],
    //         3 rels [E], 4 val [E], 5 rel_features [R*D], 6 W [D*D], 7 b [D]
    const int* heads = (const int*)d_in[1];
    const int* tails = (const int*)d_in[2];
    const int* rels  = (const int*)d_in[3];
    const float* val  = (const float*)d_in[4];
    const float* relf = (const float*)d_in[5];
    const float* W    = (const float*)d_in[6];
    const float* b    = (const float*)d_in[7];
    float* out = (float*)d_out;

    const int NUMENT = in_sizes[0];          // 16000
    const int E      = in_sizes[1];          // 2,000,000
    const int D      = in_sizes[7];          // 128
    const int R      = in_sizes[5] / D;      // 2000
    const int KP     = ((R + 63) / 64) * 64; // 2048 (K padded; pad rows are zero)

    const size_t rwbT_bytes = (size_t)D * KP * sizeof(ushort_t);       // 512 KB
    const size_t S_off      = (rwbT_bytes + 255) & ~(size_t)255;
    const size_t S_bytes    = (size_t)NUMENT * KP * sizeof(float);     // ~125 MB

    if (ws_size >= S_off + S_bytes) {
        ushort_t* rwbT = (ushort_t*)d_ws;
        float* S = (float*)((char*)d_ws + S_off);
        hipMemsetAsync(S, 0, S_bytes, stream);
        rwb_kernel<<<KP, 128, 0, stream>>>(relf, W, b, rwbT, R, KP);
        scatter_kernel<<<(E + 255) / 256, 256, 0, stream>>>(heads, tails, rels, val, S, E, KP);
        gemm_kernel<<<(NUMENT + 63) / 64, 256, 0, stream>>>(S, rwbT, out, NUMENT, KP);
    } else {
        // fallback: accumulate directly into out (slow but small-ws safe)
        float* rwb = (float*)d_ws;           // R*D fp32 (~1 MB)
        hipMemsetAsync(out, 0, (size_t)out_size * sizeof(float), stream);
        rwb_f32_kernel<<<R, 128, 0, stream>>>(relf, W, b, rwb, R);
        const long long items = (long long)E * 32;
        scatter_vec_kernel<<<(unsigned)((items + 255) / 256), 256, 0, stream>>>(
            heads, tails, rels, val, rwb, out, items);
        relu_kernel<<<(out_size / 4 + 255) / 256, 256, 0, stream>>>(out, out_size / 4);
    }
}

// Round 2
// 341.134 us; speedup vs baseline: 1.0738x; 1.0738x over previous
//
#include <hip/hip_runtime.h>
#include <hip/hip_bf16.h>
#include <cstdint>

typedef unsigned short ushort_t;
typedef _Float16 half8 __attribute__((ext_vector_type(8)));
typedef _Float16 half2v __attribute__((ext_vector_type(2)));
typedef float floatx4 __attribute__((ext_vector_type(4)));
typedef ushort_t ushort8 __attribute__((ext_vector_type(8)));

// ---------------------------------------------------------------------------
// Kernel 1: RWB_T[n][k] = dot(rel_features[k,:], W[n,:]) + b[n]   (fp16, [128][KP])
// Stored transposed ([N][K]) so the GEMM B-fragment load mirrors the A load.
// k >= R rows are zero (K padding contributes nothing).
// ---------------------------------------------------------------------------
__global__ void rwb_kernel(const float* __restrict__ rel, const float* __restrict__ W,
                           const float* __restrict__ b, _Float16* __restrict__ rwbT,
                           int R, int KP) {
    const int k = blockIdx.x;        // relation index (0..KP-1)
    const int n = threadIdx.x;       // output feature (0..127)
    __shared__ float relk[128];
    if (k < R) relk[n] = rel[(size_t)k * 128 + n];
    __syncthreads();
    float acc = 0.f;
    if (k < R) {
        const float4* w4 = reinterpret_cast<const float4*>(W + (size_t)n * 128);
        const float4* r4 = reinterpret_cast<const float4*>(relk);
#pragma unroll
        for (int i = 0; i < 32; ++i) {
            float4 a = r4[i], w = w4[i];
            acc += a.x * w.x + a.y * w.y + a.z * w.z + a.w * w.w;
        }
        acc += b[n];
    }
    rwbT[(size_t)n * KP + k] = (_Float16)acc;
}

// ---------------------------------------------------------------------------
// Kernel 2: S[v][r] += val  for v in {tail, head}   (fp16 packed, [NUM_ENT][KP])
// global_atomic_pk_add_f16: adds {val,0} or {0,val}; neighbor gets x+0=x exact.
// Halves the random-line footprint vs fp32 (65.5 MB vs 131 MB).
// ---------------------------------------------------------------------------
__global__ void scatter_kernel(const int* __restrict__ heads, const int* __restrict__ tails,
                               const int* __restrict__ rels, const float* __restrict__ val,
                               half2v* __restrict__ S2, int E, int KP2) {
    const int i = blockIdx.x * blockDim.x + threadIdx.x;
    if (i >= E) return;
    const int r = rels[i];
    const _Float16 hv = (_Float16)val[i];
    half2v add;
    add[0] = (r & 1) ? (_Float16)0.f : hv;
    add[1] = (r & 1) ? hv : (_Float16)0.f;
    const int c = r >> 1;
    __builtin_amdgcn_global_atomic_fadd_v2f16(&S2[(size_t)tails[i] * KP2 + c], add);
    __builtin_amdgcn_global_atomic_fadd_v2f16(&S2[(size_t)heads[i] * KP2 + c], add);
}

// ---------------------------------------------------------------------------
// Kernel 3: out = relu(S @ RWB)  — fp16 MFMA GEMM
// M=16000 (64/block), N=128 (full), K=KP (BK=32). 4 waves: 2x2 over (64m,128n),
// each wave 32x64 -> acc[2][4] of 16x16 tiles. S already fp16 — no convert.
// ---------------------------------------------------------------------------
__global__ __launch_bounds__(256, 2) void gemm_kernel(
    const ushort_t* __restrict__ S, const ushort_t* __restrict__ rwbT,
    float* __restrict__ out, int M, int KP) {
    __shared__ ushort_t As[64 * 32];    // 4 KB  (fp16 bits)
    __shared__ ushort_t Bs[128 * 32];   // 8 KB

    const int t = threadIdx.x;
    const int lane = t & 63;
    const int wave = t >> 6;
    const int m0 = blockIdx.x * 64;
    const int wm = (wave >> 1) * 32;   // wave m offset: 0 / 32
    const int wn = (wave & 1) * 64;    // wave n offset: 0 / 64

    // staging assignments
    const int a_r = t >> 2;            // 0..63   (S row within tile)
    const int a_c = (t & 3) * 8;       // 0,8,16,24
    const int b_r = t >> 1;            // 0..127  (rwbT row = n)
    const int b_c = (t & 1) * 16;      // 0,16

    // fragment addressing
    const int fr = lane & 15;          // m (A) or n (B) within 16-tile
    const int ko = (lane >> 4) * 8;    // k offset within BK=32

    floatx4 acc[2][4] = {};

    const bool a_ok = (m0 + a_r) < M;
    const ushort_t* aptr = S + (size_t)(m0 + a_r) * KP + a_c;
    const ushort_t* bptr = rwbT + (size_t)b_r * KP + b_c;

    for (int k0 = 0; k0 < KP; k0 += 32) {
        // stage A (already fp16): 16 B per thread
        ushort8 apk = {0, 0, 0, 0, 0, 0, 0, 0};
        if (a_ok) apk = *reinterpret_cast<const ushort8*>(aptr + k0);
        *reinterpret_cast<ushort8*>(&As[a_r * 32 + a_c]) = apk;
        // stage B: 32 B per thread
        float4 w0 = *reinterpret_cast<const float4*>(bptr + k0);
        float4 w1 = *reinterpret_cast<const float4*>(bptr + k0 + 8);
        *reinterpret_cast<float4*>(&Bs[b_r * 32 + b_c]) = w0;
        *reinterpret_cast<float4*>(&Bs[b_r * 32 + b_c + 8]) = w1;
        __syncthreads();

        half8 af[2], bfv[4];
#pragma unroll
        for (int mi = 0; mi < 2; ++mi)
            af[mi] = *reinterpret_cast<const half8*>(&As[(wm + mi * 16 + fr) * 32 + ko]);
#pragma unroll
        for (int ni = 0; ni < 4; ++ni)
            bfv[ni] = *reinterpret_cast<const half8*>(&Bs[(wn + ni * 16 + fr) * 32 + ko]);
#pragma unroll
        for (int mi = 0; mi < 2; ++mi)
#pragma unroll
            for (int ni = 0; ni < 4; ++ni)
                acc[mi][ni] = __builtin_amdgcn_mfma_f32_16x16x32_f16(
                    af[mi], bfv[ni], acc[mi][ni], 0, 0, 0);
        __syncthreads();
    }

    // epilogue: C/D layout col=lane&15, row=(lane>>4)*4+reg  [m89-verified]
    const int rbase = (lane >> 4) * 4;
#pragma unroll
    for (int mi = 0; mi < 2; ++mi)
#pragma unroll
        for (int ni = 0; ni < 4; ++ni)
#pragma unroll
            for (int g = 0; g < 4; ++g) {
                const int m = m0 + wm + mi * 16 + rbase + g;
                const int n = wn + ni * 16 + fr;
                if (m < M) out[(size_t)m * 128 + n] = fmaxf(acc[mi][ni][g], 0.f);
            }
}

// ---------------------------------------------------------------------------
// Fallback path (only if ws too small for S): direct vector scatter into out.
// ---------------------------------------------------------------------------
__global__ void rwb_f32_kernel(const float* __restrict__ rel, const float* __restrict__ W,
                               const float* __restrict__ b, float* __restrict__ rwb, int R) {
    const int k = blockIdx.x;
    const int n = threadIdx.x;
    __shared__ float relk[128];
    relk[n] = rel[(size_t)k * 128 + n];
    __syncthreads();
    const float4* w4 = reinterpret_cast<const float4*>(W + (size_t)n * 128);
    const float4* r4 = reinterpret_cast<const float4*>(relk);
    float acc = 0.f;
#pragma unroll
    for (int i = 0; i < 32; ++i) {
        float4 a = r4[i], w = w4[i];
        acc += a.x * w.x + a.y * w.y + a.z * w.z + a.w * w.w;
    }
    rwb[(size_t)k * 128 + n] = acc + b[n];
}

__global__ void scatter_vec_kernel(const int* __restrict__ heads, const int* __restrict__ tails,
                                   const int* __restrict__ rels, const float* __restrict__ val,
                                   const float* __restrict__ rwb, float* __restrict__ out,
                                   long long nitems) {
    const long long i = (long long)blockIdx.x * blockDim.x + threadIdx.x;
    if (i >= nitems) return;
    const int e = (int)(i >> 5);
    const int c = (int)(i & 31) * 4;
    const float v = val[e];
    float4 rw = *reinterpret_cast<const float4*>(rwb + (size_t)rels[e] * 128 + c);
    float* pt = out + (size_t)tails[e] * 128 + c;
    float* ph = out + (size_t)heads[e] * 128 + c;
    unsafeAtomicAdd(pt + 0, v * rw.x); unsafeAtomicAdd(pt + 1, v * rw.y);
    unsafeAtomicAdd(pt + 2, v * rw.z); unsafeAtomicAdd(pt + 3, v * rw.w);
    unsafeAtomicAdd(ph + 0, v * rw.x); unsafeAtomicAdd(ph + 1, v * rw.y);
    unsafeAtomicAdd(ph + 2, v * rw.z); unsafeAtomicAdd(ph + 3, v * rw.w);
}

__global__ void relu_kernel(float* __restrict__ out, int n4) {
    const int i = blockIdx.x * blockDim.x + threadIdx.x;
    if (i >= n4) return;
    float4* p = reinterpret_cast<float4*>(out) + i;
    float4 v = *p;
    v.x = fmaxf(v.x, 0.f); v.y = fmaxf(v.y, 0.f);
    v.z = fmaxf(v.z, 0.f); v.w = fmaxf(v.w, 0.f);
    *p = v;
}

// ---------------------------------------------------------------------------
extern "C" void kernel_launch(void* const* d_in, const int* in_sizes, int n_in,
                              void* d_out, int out_size, void* d_ws, size_t ws_size,
                              hipStream_t stream) {
    // inputs: 0 local_entity [B*M] (shape only), 1 heads [E], 2 tails [E],
    //         3 rels [E], 4 val [E], 5 rel_features [R*D], 6 W [D*D], 7 b [D]
    const int* heads = (const int*)d_in[1];
    const int* tails = (const int*)d_in[2];
    const int* rels  = (const int*)d_in[3];
    const float* val  = (const float*)d_in[4];
    const float* relf = (const float*)d_in[5];
    const float* W    = (const float*)d_in[6];
    const float* b    = (const float*)d_in[7];
    float* out = (float*)d_out;

    const int NUMENT = in_sizes[0];          // 16000
    const int E      = in_sizes[1];          // 2,000,000
    const int D      = in_sizes[7];          // 128
    const int R      = in_sizes[5] / D;      // 2000
    const int KP     = ((R + 63) / 64) * 64; // 2048 (K padded; pad rows are zero)

    const size_t rwbT_bytes = (size_t)D * KP * sizeof(_Float16);        // 512 KB
    const size_t S_off      = (rwbT_bytes + 255) & ~(size_t)255;
    const size_t S_bytes    = (size_t)NUMENT * KP * sizeof(_Float16);   // ~65.5 MB

    if (ws_size >= S_off + S_bytes) {
        _Float16* rwbT = (_Float16*)d_ws;
        half2v* S2 = (half2v*)((char*)d_ws + S_off);
        hipMemsetAsync(S2, 0, S_bytes, stream);
        rwb_kernel<<<KP, 128, 0, stream>>>(relf, W, b, rwbT, R, KP);
        scatter_kernel<<<(E + 255) / 256, 256, 0, stream>>>(heads, tails, rels, val, S2, E, KP / 2);
        gemm_kernel<<<(NUMENT + 63) / 64, 256, 0, stream>>>(
            (const ushort_t*)S2, (const ushort_t*)rwbT, out, NUMENT, KP);
    } else {
        // fallback: accumulate directly into out (slow but small-ws safe)
        float* rwb = (float*)d_ws;           // R*D fp32 (~1 MB)
        hipMemsetAsync(out, 0, (size_t)out_size * sizeof(float), stream);
        rwb_f32_kernel<<<R, 128, 0, stream>>>(relf, W, b, rwb, R);
        const long long items = (long long)E * 32;
        scatter_vec_kernel<<<(unsigned)((items + 255) / 256), 256, 0, stream>>>(
            heads, tails, rels, val, rwb, out, items);
        relu_kernel<<<(out_size / 4 + 255) / 256, 256, 0, stream>>>(out, out_size / 4);
    }
}